// Round 15
// baseline (79.540 us; speedup 1.0000x reference)
//
#include <hip/hip_runtime.h>

#define TSD 512      // TS (feature dim)
#define SRC 256
#define TGT 256
#define NB  4        // batch
#define KSCALE 2.885390081777927f       // 2*log2(e): exp2(K*x) == exp(2x)
#define SCALE  9.5367431640625e-07f     // 2^-20: overflow headroom for 4-way product
#define EPSV   1e-20f

// ---------------------------------------------------------------------------
// Projection GEMM, re-tiled for occupancy: 32x32 tiles, 2x2 micro, BK=32.
// Grid (TSD/32=16, 1024/32=32, 2) = 1024 blocks (4/CU), 256 thr = 4 waves.
// z=0: hpE2[r][o]   = S * exp2(K*(hid.Wh)[r][o]) / v[o]       (row-major)
// z=1: epE[b][o][s] = exp2(K*((enc.We)[r][o] + bias[o]))      (TRANSPOSED)
// ---------------------------------------------------------------------------
__global__ __launch_bounds__(256) void proj_kernel(
    const float* __restrict__ hid, const float* __restrict__ enc,
    const float* __restrict__ W, const float* __restrict__ bias,
    const float* __restrict__ v,
    float* __restrict__ hpE2, float* __restrict__ epE)
{
    const int z = blockIdx.z;
    const float* __restrict__ X = z ? enc : hid;
    const int wofs = z ? TSD : 0;

    __shared__ float Xs[32][36];   // [k][m]
    __shared__ float Ws[32][36];   // [k][n]
    __shared__ float tile[32][33]; // transpose staging (z=1), pad 33

    const int tid = threadIdx.x;
    const int tx = tid & 15, ty = tid >> 4;
    const int o0 = blockIdx.x * 32;
    const int r0 = blockIdx.y * 32;

    const int srow = tid >> 3;        // 0..31 (staging row)
    const int skq  = (tid & 7) * 4;   // 0,4,...,28

    float acc[2][2] = {};

    for (int k0 = 0; k0 < TSD; k0 += 32) {
        __syncthreads();
        float4 av = *reinterpret_cast<const float4*>(&X[(r0 + srow) * TSD + k0 + skq]);
        float4 wv = *reinterpret_cast<const float4*>(&W[(o0 + srow) * (2 * TSD) + wofs + k0 + skq]);
        Xs[skq + 0][srow] = av.x; Xs[skq + 1][srow] = av.y;
        Xs[skq + 2][srow] = av.z; Xs[skq + 3][srow] = av.w;
        Ws[skq + 0][srow] = wv.x; Ws[skq + 1][srow] = wv.y;
        Ws[skq + 2][srow] = wv.z; Ws[skq + 3][srow] = wv.w;
        __syncthreads();
        #pragma unroll
        for (int k = 0; k < 32; ++k) {
            const float2 a = *reinterpret_cast<const float2*>(&Xs[k][ty * 2]);
            const float2 b = *reinterpret_cast<const float2*>(&Ws[k][tx * 2]);
            acc[0][0] = fmaf(a.x, b.x, acc[0][0]);
            acc[0][1] = fmaf(a.x, b.y, acc[0][1]);
            acc[1][0] = fmaf(a.y, b.x, acc[1][0]);
            acc[1][1] = fmaf(a.y, b.y, acc[1][1]);
        }
    }

    if (z) {
        // exp2(K*(acc+bias)) -> LDS tile [s][o] -> coalesced transposed store
        const float bj0 = bias[o0 + tx * 2 + 0];
        const float bj1 = bias[o0 + tx * 2 + 1];
        #pragma unroll
        for (int i = 0; i < 2; ++i) {
            tile[ty * 2 + i][tx * 2 + 0] =
                __builtin_amdgcn_exp2f((acc[i][0] + bj0) * KSCALE);
            tile[ty * 2 + i][tx * 2 + 1] =
                __builtin_amdgcn_exp2f((acc[i][1] + bj1) * KSCALE);
        }
        __syncthreads();
        const int bb_   = r0 >> 8;
        const int sbase = r0 & 255;
        const int sl = tid & 31;
        #pragma unroll
        for (int p = 0; p < 4; ++p) {
            const int ol = p * 8 + (tid >> 5);
            epE[((size_t)bb_ * TSD + o0 + ol) * SRC + sbase + sl] = tile[sl][ol];
        }
    } else {
        const int oc = o0 + tx * 2;
        const float iv0 = SCALE * __builtin_amdgcn_rcpf(fmaxf(v[oc + 0], EPSV));
        const float iv1 = SCALE * __builtin_amdgcn_rcpf(fmaxf(v[oc + 1], EPSV));
        #pragma unroll
        for (int i = 0; i < 2; ++i) {
            const int r = r0 + ty * 2 + i;
            float2 o2;
            o2.x = __builtin_amdgcn_exp2f(acc[i][0] * KSCALE) * iv0;
            o2.y = __builtin_amdgcn_exp2f(acc[i][1] * KSCALE) * iv1;
            *reinterpret_cast<float2*>(&hpE2[(size_t)r * TSD + oc]) = o2;
        }
    }
}

__device__ __forceinline__ float wave_red_sum(float v) {
    #pragma unroll
    for (int off = 1; off < 64; off <<= 1) v += __shfl_xor(v, off, 64);
    return v;
}
__device__ __forceinline__ float wave_red_max(float v) {
    #pragma unroll
    for (int off = 1; off < 64; off <<= 1) v = fmaxf(v, __shfl_xor(v, off, 64));
    return v;
}

// 4 t-rows at one s: w_t = eh_t*ee + iv (one fma each); 4 terms share one rcp
#define GRP4(EH, EE, IV, A0, A1, A2, A3) {                        \
    const float w0_ = fmaf((EH).x, (EE), IV);                     \
    const float w1_ = fmaf((EH).y, (EE), IV);                     \
    const float w2_ = fmaf((EH).z, (EE), IV);                     \
    const float w3_ = fmaf((EH).w, (EE), IV);                     \
    const float p01_ = w0_ * w1_;                                 \
    const float p23_ = w2_ * w3_;                                 \
    const float r_   = __builtin_amdgcn_rcpf(p01_ * p23_);        \
    const float rp01_ = r_ * p01_;                                \
    const float rp23_ = r_ * p23_;                                \
    A0 = fmaf(rp23_, w1_, A0); A1 = fmaf(rp23_, w0_, A1);         \
    A2 = fmaf(rp01_, w3_, A2); A3 = fmaf(rp01_, w2_, A3); }

// ---------------------------------------------------------------------------
// Fused score + softmax + context (R13-proven, unchanged).
// Grid (TGT/4, NB), 1024 thr = 16 waves; wave: s-half = w>>3, o-slice = w&7.
// ---------------------------------------------------------------------------
__global__ __launch_bounds__(1024) void attn_fused_kernel(
    const float* __restrict__ hpE2, const float* __restrict__ epE,
    const float* __restrict__ v, const int* __restrict__ mask,
    const float* __restrict__ enc,
    float* __restrict__ ctx_out, float* __restrict__ probs_out)
{
    __shared__ float4 eh4[TSD];       // Eh2s packed by t       (8 KB)
    __shared__ float  ivs[TSD];       // S/v[o]                 (2 KB)
    __shared__ float  red8[8][SRC];   // o-slice partials       (8 KB, reused per t)
    __shared__ float  Plds[4][SRC];   // P, then probs          (4 KB)
    __shared__ float  redgA[4][4];
    __shared__ float  redgB[4][4];

    const int tid = threadIdx.x;
    const int b  = blockIdx.y;
    const int t0 = blockIdx.x * 4;

    // ---- stage Eh2s (4 rows packed per o) + ivs ----
    if (tid < 512) {
        const int row = tid >> 7;            // 0..3
        const int oq  = (tid & 127) * 4;
        const float4 hh = *reinterpret_cast<const float4*>(
            &hpE2[((size_t)(b * TGT + t0 + row)) * TSD + oq]);
        ((float*)&eh4[oq + 0])[row] = hh.x;
        ((float*)&eh4[oq + 1])[row] = hh.y;
        ((float*)&eh4[oq + 2])[row] = hh.z;
        ((float*)&eh4[oq + 3])[row] = hh.w;
    } else {
        const int o = tid - 512;
        ivs[o] = SCALE * __builtin_amdgcn_rcpf(fmaxf(v[o], EPSV));
    }
    __syncthreads();

    // ---- score partials ----
    const int w    = __builtin_amdgcn_readfirstlane(tid >> 6);  // wave 0..15
    const int lane = tid & 63;
    const int sh   = w >> 3;                                    // s-half
    const int ow   = w & 7;                                     // o-slice
    const int obase = ow * 64;
    const float* __restrict__ epb =
        epE + (size_t)b * TSD * SRC + (size_t)obase * SRC + sh * 128 + 2 * lane;

    float acc[4][2] = {};   // [t][s-sub]
    #pragma unroll 4
    for (int oi = 0; oi < 64; ++oi) {
        const int o = obase + oi;
        const float2 ee = *reinterpret_cast<const float2*>(epb + (size_t)oi * SRC);
        const float4 eh = eh4[o];       // uniform -> ds_read_b128 broadcast
        const float  iv = ivs[o];       // uniform -> ds_read_b32 broadcast
        GRP4(eh, ee.x, iv, acc[0][0], acc[1][0], acc[2][0], acc[3][0])
        GRP4(eh, ee.y, iv, acc[0][1], acc[1][1], acc[2][1], acc[3][1])
    }

    // ---- combine 8 o-slices per t (red8 reused across t) ----
    #pragma unroll
    for (int t = 0; t < 4; ++t) {
        __syncthreads();
        float2 r2; r2.x = acc[t][0]; r2.y = acc[t][1];
        *reinterpret_cast<float2*>(&red8[ow][sh * 128 + 2 * lane]) = r2;
        __syncthreads();
        if (tid < SRC) {
            float Ps = 0.f;
            #pragma unroll
            for (int r = 0; r < 8; ++r) Ps += red8[r][tid];
            Plds[t][tid] = Ps * SCALE;
        }
    }
    __syncthreads();

    // ---- softmax: group g = tid>>8 handles row t0+g, s = tid&255 ----
    const int g = __builtin_amdgcn_readfirstlane(tid >> 8);
    const int s = tid & 255;
    const int wig = (tid >> 6) & 3;

    float sv = v[s] + v[s + 256];
    {
        float wsv = wave_red_sum(sv);
        if ((tid & 63) == 0) redgA[g][wig] = wsv;
    }
    __syncthreads();
    const float sumv = redgA[g][0] + redgA[g][1] + redgA[g][2] + redgA[g][3];
    const float score = sumv - 2.f * Plds[g][s];

    {
        float wm = wave_red_max(score);
        if ((tid & 63) == 0) redgB[g][wig] = wm;
    }
    __syncthreads();
    const float mx = fmaxf(fmaxf(redgB[g][0], redgB[g][1]), fmaxf(redgB[g][2], redgB[g][3]));
    const float e = __expf(score - mx);
    {
        float ws = wave_red_sum(e);
        if ((tid & 63) == 0) redgA[g][wig] = ws;
    }
    __syncthreads();
    const float sE = redgA[g][0] + redgA[g][1] + redgA[g][2] + redgA[g][3];
    const float mq = (e / sE) * (float)mask[b * SRC + s];
    {
        float ws = wave_red_sum(mq);
        if ((tid & 63) == 0) redgB[g][wig] = ws;
    }
    __syncthreads();
    const float sM = redgB[g][0] + redgB[g][1] + redgB[g][2] + redgB[g][3];
    const float p = mq / (sM + 1e-12f);
    __syncthreads();
    Plds[g][s] = p;
    probs_out[((size_t)(b * TGT + t0 + g)) * SRC + s] = p;
    __syncthreads();

    // ---- context: dg = tid>>9 handles rows {2dg, 2dg+1}; d = tid&511 ----
    const int dg = tid >> 9;
    const int d  = tid & 511;
    const float* __restrict__ encb = enc + (size_t)b * SRC * TSD + d;
    float c0 = 0.f, c1 = 0.f;
    #pragma unroll 4
    for (int s2 = 0; s2 < SRC; ++s2) {
        const float ev = encb[(size_t)s2 * TSD];
        c0 = fmaf(Plds[2 * dg + 0][s2], ev, c0);
        c1 = fmaf(Plds[2 * dg + 1][s2], ev, c1);
    }
    ctx_out[((size_t)(b * TGT + t0 + 2 * dg + 0)) * TSD + d] = c0;
    ctx_out[((size_t)(b * TGT + t0 + 2 * dg + 1)) * TSD + d] = c1;
}

extern "C" void kernel_launch(void* const* d_in, const int* in_sizes, int n_in,
                              void* d_out, int out_size, void* d_ws, size_t ws_size,
                              hipStream_t stream) {
    const float* hid  = (const float*)d_in[0];   // (4,256,512)
    const float* enc  = (const float*)d_in[1];   // (4,256,512)
    const int*   mask = (const int*)  d_in[2];   // (4,256)
    const float* W    = (const float*)d_in[3];   // (512,1024)
    const float* bias = (const float*)d_in[4];   // (512,)
    const float* v    = (const float*)d_in[5];   // (512,)

    float* out   = (float*)d_out;
    float* ctx   = out;                       // 4*256*512
    float* probs = out + NB * TGT * TSD;      // 4*256*256

    float* hpE2 = (float*)d_ws;               // 1024*512: S*exp2(K*h)/v    2 MB
    float* epE  = hpE2 + NB * TGT * TSD;      // 4*512*256: exp2(K*(e+b))^T 2 MB

    dim3 pg(TSD / 32, (NB * TGT) / 32, 2);
    proj_kernel<<<pg, 256, 0, stream>>>(hid, enc, W, bias, v, hpE2, epE);

    dim3 ag(TGT / 4, NB);
    attn_fused_kernel<<<ag, 1024, 0, stream>>>(hpE2, epE, v, mask, enc, ctx, probs);
}

// Round 16
// 75.301 us; speedup vs baseline: 1.0563x; 1.0563x over previous
//
#include <hip/hip_runtime.h>

#define TSD 512      // TS (feature dim)
#define SRC 256
#define TGT 256
#define NB  4        // batch
#define KSCALE 2.885390081777927f       // 2*log2(e): exp2(K*x) == exp(2x)
#define SCALE  9.5367431640625e-07f     // 2^-20: overflow headroom for 4-way product
#define EPSV   1e-20f

// ---------------------------------------------------------------------------
// Projection GEMM: 64x64 tile, 8x4 micro-tile, 128 threads, BK=16.
// Grid (TSD/64=8, 1024/64=16, 2) = 256 blocks (1/CU, all CUs).
// Per k-iter: 3 ds_read_b128 per 32 fma (vs 2 per 16 in 4x4) -> 25% fewer
// LDS instrs; proj is LDS-read-throughput-bound.
// z=0: hpE2[r][o]   = S * exp2(K*(hid.Wh)[r][o]) / v[o]       (row-major)
// z=1: epE[b][o][s] = exp2(K*((enc.We)[r][o] + bias[o]))      (TRANSPOSED)
// ---------------------------------------------------------------------------
__global__ __launch_bounds__(128) void proj_kernel(
    const float* __restrict__ hid, const float* __restrict__ enc,
    const float* __restrict__ W, const float* __restrict__ bias,
    const float* __restrict__ v,
    float* __restrict__ hpE2, float* __restrict__ epE)
{
    const int z = blockIdx.z;
    const float* __restrict__ X = z ? enc : hid;
    const int wofs = z ? TSD : 0;

    __shared__ float Xs[16][68];   // [k][m]
    __shared__ float Ws[16][68];   // [k][n]
    __shared__ float tile[64][68]; // transpose staging (z=1)

    const int tid = threadIdx.x;   // 0..127
    const int tx = tid & 15;       // col group (4 cols)
    const int ty = tid >> 4;       // 0..7, row group (8 rows)
    const int o0 = blockIdx.x * 64;
    const int r0 = blockIdx.y * 64;

    const int m  = tid >> 1;       // 0..63 (staging row)
    const int kq = (tid & 1) * 8;  // 0 or 8

    float acc[8][4] = {};

    for (int k0 = 0; k0 < TSD; k0 += 16) {
        __syncthreads();
        float4 av0 = *reinterpret_cast<const float4*>(&X[(r0 + m) * TSD + k0 + kq]);
        float4 av1 = *reinterpret_cast<const float4*>(&X[(r0 + m) * TSD + k0 + kq + 4]);
        float4 wv0 = *reinterpret_cast<const float4*>(&W[(o0 + m) * (2 * TSD) + wofs + k0 + kq]);
        float4 wv1 = *reinterpret_cast<const float4*>(&W[(o0 + m) * (2 * TSD) + wofs + k0 + kq + 4]);
        Xs[kq + 0][m] = av0.x; Xs[kq + 1][m] = av0.y; Xs[kq + 2][m] = av0.z; Xs[kq + 3][m] = av0.w;
        Xs[kq + 4][m] = av1.x; Xs[kq + 5][m] = av1.y; Xs[kq + 6][m] = av1.z; Xs[kq + 7][m] = av1.w;
        Ws[kq + 0][m] = wv0.x; Ws[kq + 1][m] = wv0.y; Ws[kq + 2][m] = wv0.z; Ws[kq + 3][m] = wv0.w;
        Ws[kq + 4][m] = wv1.x; Ws[kq + 5][m] = wv1.y; Ws[kq + 6][m] = wv1.z; Ws[kq + 7][m] = wv1.w;
        __syncthreads();
        #pragma unroll
        for (int k = 0; k < 16; ++k) {
            float4 alo = *reinterpret_cast<const float4*>(&Xs[k][ty * 8]);
            float4 ahi = *reinterpret_cast<const float4*>(&Xs[k][ty * 8 + 4]);
            float4 b   = *reinterpret_cast<const float4*>(&Ws[k][tx * 4]);
            float ar[8] = {alo.x, alo.y, alo.z, alo.w, ahi.x, ahi.y, ahi.z, ahi.w};
            float br[4] = {b.x, b.y, b.z, b.w};
            #pragma unroll
            for (int i = 0; i < 8; ++i)
                #pragma unroll
                for (int j = 0; j < 4; ++j)
                    acc[i][j] = fmaf(ar[i], br[j], acc[i][j]);
        }
    }

    if (z) {
        // exp2(K*(acc+bias)) -> tile[s][o] -> coalesced transposed store
        const float bj0 = bias[o0 + tx * 4 + 0];
        const float bj1 = bias[o0 + tx * 4 + 1];
        const float bj2 = bias[o0 + tx * 4 + 2];
        const float bj3 = bias[o0 + tx * 4 + 3];
        __syncthreads();
        #pragma unroll
        for (int i = 0; i < 8; ++i) {
            const int row = ty * 8 + i;
            tile[row][tx * 4 + 0] = __builtin_amdgcn_exp2f((acc[i][0] + bj0) * KSCALE);
            tile[row][tx * 4 + 1] = __builtin_amdgcn_exp2f((acc[i][1] + bj1) * KSCALE);
            tile[row][tx * 4 + 2] = __builtin_amdgcn_exp2f((acc[i][2] + bj2) * KSCALE);
            tile[row][tx * 4 + 3] = __builtin_amdgcn_exp2f((acc[i][3] + bj3) * KSCALE);
        }
        __syncthreads();
        const int bb_   = r0 >> 8;
        const int sbase = r0 & 255;
        const int sl    = tid & 63;
        const int oh    = tid >> 6;     // 0..1
        #pragma unroll
        for (int p = 0; p < 32; ++p) {
            const int ol = p * 2 + oh;
            epE[((size_t)bb_ * TSD + o0 + ol) * SRC + sbase + sl] = tile[sl][ol];
        }
    } else {
        const int oc = o0 + tx * 4;
        float iv[4];
        #pragma unroll
        for (int j = 0; j < 4; ++j)
            iv[j] = SCALE * __builtin_amdgcn_rcpf(fmaxf(v[oc + j], EPSV));
        #pragma unroll
        for (int i = 0; i < 8; ++i) {
            const int r = r0 + ty * 8 + i;
            float4 o4;
            o4.x = __builtin_amdgcn_exp2f(acc[i][0] * KSCALE) * iv[0];
            o4.y = __builtin_amdgcn_exp2f(acc[i][1] * KSCALE) * iv[1];
            o4.z = __builtin_amdgcn_exp2f(acc[i][2] * KSCALE) * iv[2];
            o4.w = __builtin_amdgcn_exp2f(acc[i][3] * KSCALE) * iv[3];
            *reinterpret_cast<float4*>(&hpE2[(size_t)r * TSD + oc]) = o4;
        }
    }
}

__device__ __forceinline__ float wave_red_sum(float v) {
    #pragma unroll
    for (int off = 1; off < 64; off <<= 1) v += __shfl_xor(v, off, 64);
    return v;
}
__device__ __forceinline__ float wave_red_max(float v) {
    #pragma unroll
    for (int off = 1; off < 64; off <<= 1) v = fmaxf(v, __shfl_xor(v, off, 64));
    return v;
}

// 4 t-rows at one s: w_t = eh_t*ee + iv (one fma each); 4 terms share one rcp
#define GRP4(EH, EE, IV, A0, A1, A2, A3) {                        \
    const float w0_ = fmaf((EH).x, (EE), IV);                     \
    const float w1_ = fmaf((EH).y, (EE), IV);                     \
    const float w2_ = fmaf((EH).z, (EE), IV);                     \
    const float w3_ = fmaf((EH).w, (EE), IV);                     \
    const float p01_ = w0_ * w1_;                                 \
    const float p23_ = w2_ * w3_;                                 \
    const float r_   = __builtin_amdgcn_rcpf(p01_ * p23_);        \
    const float rp01_ = r_ * p01_;                                \
    const float rp23_ = r_ * p23_;                                \
    A0 = fmaf(rp23_, w1_, A0); A1 = fmaf(rp23_, w0_, A1);         \
    A2 = fmaf(rp01_, w3_, A2); A3 = fmaf(rp01_, w2_, A3); }

// ---------------------------------------------------------------------------
// Fused score + softmax + context (R13-proven, unchanged).
// Grid (TGT/4, NB), 1024 thr = 16 waves; wave: s-half = w>>3, o-slice = w&7.
// ---------------------------------------------------------------------------
__global__ __launch_bounds__(1024) void attn_fused_kernel(
    const float* __restrict__ hpE2, const float* __restrict__ epE,
    const float* __restrict__ v, const int* __restrict__ mask,
    const float* __restrict__ enc,
    float* __restrict__ ctx_out, float* __restrict__ probs_out)
{
    __shared__ float4 eh4[TSD];       // Eh2s packed by t       (8 KB)
    __shared__ float  ivs[TSD];       // S/v[o]                 (2 KB)
    __shared__ float  red8[8][SRC];   // o-slice partials       (8 KB, reused per t)
    __shared__ float  Plds[4][SRC];   // P, then probs          (4 KB)
    __shared__ float  redgA[4][4];
    __shared__ float  redgB[4][4];

    const int tid = threadIdx.x;
    const int b  = blockIdx.y;
    const int t0 = blockIdx.x * 4;

    // ---- stage Eh2s (4 rows packed per o) + ivs ----
    if (tid < 512) {
        const int row = tid >> 7;            // 0..3
        const int oq  = (tid & 127) * 4;
        const float4 hh = *reinterpret_cast<const float4*>(
            &hpE2[((size_t)(b * TGT + t0 + row)) * TSD + oq]);
        ((float*)&eh4[oq + 0])[row] = hh.x;
        ((float*)&eh4[oq + 1])[row] = hh.y;
        ((float*)&eh4[oq + 2])[row] = hh.z;
        ((float*)&eh4[oq + 3])[row] = hh.w;
    } else {
        const int o = tid - 512;
        ivs[o] = SCALE * __builtin_amdgcn_rcpf(fmaxf(v[o], EPSV));
    }
    __syncthreads();

    // ---- score partials ----
    const int w    = __builtin_amdgcn_readfirstlane(tid >> 6);  // wave 0..15
    const int lane = tid & 63;
    const int sh   = w >> 3;                                    // s-half
    const int ow   = w & 7;                                     // o-slice
    const int obase = ow * 64;
    const float* __restrict__ epb =
        epE + (size_t)b * TSD * SRC + (size_t)obase * SRC + sh * 128 + 2 * lane;

    float acc[4][2] = {};   // [t][s-sub]
    #pragma unroll 4
    for (int oi = 0; oi < 64; ++oi) {
        const int o = obase + oi;
        const float2 ee = *reinterpret_cast<const float2*>(epb + (size_t)oi * SRC);
        const float4 eh = eh4[o];       // uniform -> ds_read_b128 broadcast
        const float  iv = ivs[o];       // uniform -> ds_read_b32 broadcast
        GRP4(eh, ee.x, iv, acc[0][0], acc[1][0], acc[2][0], acc[3][0])
        GRP4(eh, ee.y, iv, acc[0][1], acc[1][1], acc[2][1], acc[3][1])
    }

    // ---- combine 8 o-slices per t (red8 reused across t) ----
    #pragma unroll
    for (int t = 0; t < 4; ++t) {
        __syncthreads();
        float2 r2; r2.x = acc[t][0]; r2.y = acc[t][1];
        *reinterpret_cast<float2*>(&red8[ow][sh * 128 + 2 * lane]) = r2;
        __syncthreads();
        if (tid < SRC) {
            float Ps = 0.f;
            #pragma unroll
            for (int r = 0; r < 8; ++r) Ps += red8[r][tid];
            Plds[t][tid] = Ps * SCALE;
        }
    }
    __syncthreads();

    // ---- softmax: group g = tid>>8 handles row t0+g, s = tid&255 ----
    const int g = __builtin_amdgcn_readfirstlane(tid >> 8);
    const int s = tid & 255;
    const int wig = (tid >> 6) & 3;

    float sv = v[s] + v[s + 256];
    {
        float wsv = wave_red_sum(sv);
        if ((tid & 63) == 0) redgA[g][wig] = wsv;
    }
    __syncthreads();
    const float sumv = redgA[g][0] + redgA[g][1] + redgA[g][2] + redgA[g][3];
    const float score = sumv - 2.f * Plds[g][s];

    {
        float wm = wave_red_max(score);
        if ((tid & 63) == 0) redgB[g][wig] = wm;
    }
    __syncthreads();
    const float mx = fmaxf(fmaxf(redgB[g][0], redgB[g][1]), fmaxf(redgB[g][2], redgB[g][3]));
    const float e = __expf(score - mx);
    {
        float ws = wave_red_sum(e);
        if ((tid & 63) == 0) redgA[g][wig] = ws;
    }
    __syncthreads();
    const float sE = redgA[g][0] + redgA[g][1] + redgA[g][2] + redgA[g][3];
    const float mq = (e / sE) * (float)mask[b * SRC + s];
    {
        float ws = wave_red_sum(mq);
        if ((tid & 63) == 0) redgB[g][wig] = ws;
    }
    __syncthreads();
    const float sM = redgB[g][0] + redgB[g][1] + redgB[g][2] + redgB[g][3];
    const float p = mq / (sM + 1e-12f);
    __syncthreads();
    Plds[g][s] = p;
    probs_out[((size_t)(b * TGT + t0 + g)) * SRC + s] = p;
    __syncthreads();

    // ---- context: dg = tid>>9 handles rows {2dg, 2dg+1}; d = tid&511 ----
    const int dg = tid >> 9;
    const int d  = tid & 511;
    const float* __restrict__ encb = enc + (size_t)b * SRC * TSD + d;
    float c0 = 0.f, c1 = 0.f;
    #pragma unroll 4
    for (int s2 = 0; s2 < SRC; ++s2) {
        const float ev = encb[(size_t)s2 * TSD];
        c0 = fmaf(Plds[2 * dg + 0][s2], ev, c0);
        c1 = fmaf(Plds[2 * dg + 1][s2], ev, c1);
    }
    ctx_out[((size_t)(b * TGT + t0 + 2 * dg + 0)) * TSD + d] = c0;
    ctx_out[((size_t)(b * TGT + t0 + 2 * dg + 1)) * TSD + d] = c1;
}

extern "C" void kernel_launch(void* const* d_in, const int* in_sizes, int n_in,
                              void* d_out, int out_size, void* d_ws, size_t ws_size,
                              hipStream_t stream) {
    const float* hid  = (const float*)d_in[0];   // (4,256,512)
    const float* enc  = (const float*)d_in[1];   // (4,256,512)
    const int*   mask = (const int*)  d_in[2];   // (4,256)
    const float* W    = (const float*)d_in[3];   // (512,1024)
    const float* bias = (const float*)d_in[4];   // (512,)
    const float* v    = (const float*)d_in[5];   // (512,)

    float* out   = (float*)d_out;
    float* ctx   = out;                       // 4*256*512
    float* probs = out + NB * TGT * TSD;      // 4*256*256

    float* hpE2 = (float*)d_ws;               // 1024*512: S*exp2(K*h)/v    2 MB
    float* epE  = hpE2 + NB * TGT * TSD;      // 4*512*256: exp2(K*(e+b))^T 2 MB

    dim3 pg(TSD / 64, (NB * TGT) / 64, 2);
    proj_kernel<<<pg, 128, 0, stream>>>(hid, enc, W, bias, v, hpE2, epE);

    dim3 ag(TGT / 4, NB);
    attn_fused_kernel<<<ag, 1024, 0, stream>>>(hpE2, epE, v, mask, enc, ctx, probs);
}